// Round 6
// baseline (237.891 us; speedup 1.0000x reference)
//
#include <hip/hip_runtime.h>
#include <math.h>

// Peak biquad (DF2T) over (16, 2, 1<<20) fp32.
//
// R6 post-mortem: occupancy 17->38%, VALUBusy 11->23%, BW UNCHANGED at
// ~2.44 TB/s. Three different structures (R2/R5/R6) converge to the same
// service rate with ~100KB/CU outstanding (30x the Little's-law need) ->
// parallelism is not the constraint; the memory system is the cap.
//
// Evidence: FETCH_SIZE = 66MB but the input is 128MB -- half the reads are
// already Infinity-Cache hits. x(128MB) + y(128MB) = 256MB = exactly IC
// capacity: every y-store WRITE-ALLOCATES and evicts an x line -> 50%
// thrash equilibrium, HBM carries 66MB refetch + 128MB writeback through a
// churning cache. The write-only fill kernel streams 6.7 TB/s on this box.
//
// R7b = R6 + ONE change: non-temporal y-stores (evict-first, no IC
// allocation). y is never re-read by the kernel; keeping it out of the IC
// leaves x fully resident (128MB < 256MB) -> reads become ~100% LLC hits,
// HBM carries only the streaming write. (R7 failed to compile:
// __builtin_nontemporal_store rejects HIP_vector_type; store through a
// native ext_vector_type(4) pointer instead.)
// Predicted: FETCH collapses (<20GB-units), dur 83 -> ~45-60us. If FETCH
// collapses but dur doesn't move, the 2.5 TB/s cap is structural ->
// roofline.

constexpr int T_LEN   = 1 << 20;                 // samples per channel
constexpr int CH_G    = 8;                       // granules (float4) per 32-sample chunk
constexpr int THREADS = 64;                      // one wave per block
constexpr int HALO_R  = 2;                       // 2 chunk-rows = 64 warm-up samples
constexpr int ROWS    = THREADS + HALO_R;        // 66 LDS rows
constexpr int GRAN_PER_BLOCK  = THREADS * CH_G;  // 512 granules = 8 KiB
constexpr int GRAN_PER_CHAN   = T_LEN / 4;       // 262144
constexpr int BLOCKS_PER_CHAN = GRAN_PER_CHAN / GRAN_PER_BLOCK;  // 512

typedef float floatv4 __attribute__((ext_vector_type(4)));

__device__ __forceinline__ int swz(int row, int col) {
    // logical (row, col<8) -> LDS granule index; XOR spreads same-column
    // wave accesses across all 8 bank-groups (residual ~2-way is near-free).
    return (row << 3) | (col ^ (row & 7));
}

__global__ __launch_bounds__(THREADS, 4) void peak_kernel(
    const float4* __restrict__ x4,
    const float* __restrict__ p_freq_raw,
    const float* __restrict__ p_q_raw,
    const float* __restrict__ p_gain,
    float4* __restrict__ y4)
{
    __shared__ float4 buf[ROWS * CH_G];          // 528 granules = 8448 B

    const int t = threadIdx.x;
    const size_t base = (size_t)blockIdx.x * GRAN_PER_BLOCK;
    const bool chan_start = (blockIdx.x % BLOCKS_PER_CHAN) == 0;

    // ---- coefficients (scalar math; overlaps with staging loads) ----
    float fraw = p_freq_raw[0];
    float qraw = p_q_raw[0];
    float gdb  = p_gain[0];

    float sfreq = 1.0f / (1.0f + __expf(-fraw));
    float freq  = sfreq * (17500.0f - 33.0f) + 33.0f;
    float sq    = 1.0f / (1.0f + __expf(-qraw));
    float Q     = sq * (20.0f - 0.2f) + 0.2f;

    float w0    = 6.283185307179586f * freq / 44100.0f;
    float A     = expf(gdb * 0.05756462732485114f);   // 10^(g/40)
    float sw    = sinf(w0);
    float cw    = cosf(w0);
    float alpha = sw / (2.0f * Q);

    float inv_a0 = 1.0f / (1.0f + alpha / A);
    float b0  = (1.0f + alpha * A) * inv_a0;
    float b1  = (-2.0f * cw) * inv_a0;
    float b2  = (1.0f - alpha * A) * inv_a0;
    float na1 = -b1;
    float na2 = -((1.0f - alpha / A) * inv_a0);

    // ---- stage: global -> LDS, all loads issued back-to-back ----
    // halo rows 0..1 = the 64 samples preceding this block's region
    if (t < HALO_R * CH_G) {                     // lanes 0..15
        float4 h = make_float4(0.f, 0.f, 0.f, 0.f);
        if (!chan_start) h = x4[base - HALO_R * CH_G + t];
        buf[swz(t >> 3, t & 7)] = h;
    }
    // tile rows 2..65 (8 coalesced 1KB wave-loads)
#pragma unroll
    for (int i = 0; i < CH_G; ++i) {
        const int g = (i << 6) | t;              // 0..511, lane-contiguous
        buf[swz(HALO_R + (g >> 3), g & 7)] = x4[base + g];
    }
    __syncthreads();

    // ---- warm-up: 64 samples = extended rows t, t+1 (discard outputs) ----
    float s1 = 0.f, s2 = 0.f;
#pragma unroll
    for (int r = 0; r < HALO_R; ++r) {
        const int row = t + r;
#pragma unroll
        for (int j = 0; j < CH_G; ++j) {
            float4 xv = buf[swz(row, j)];
#pragma unroll
            for (int q = 0; q < 4; ++q) {
                float xt = (&xv.x)[q];
                float yv = fmaf(b0, xt, s1);
                s1 = fmaf(b1, xt, s2);
                s1 = fmaf(na1, yv, s1);
                s2 = xt * b2;
                s2 = fmaf(na2, yv, s2);
            }
        }
    }
    __syncthreads();   // all warm-up reads done before rows are overwritten

    // ---- main: own chunk = extended row t+2, overwrite x with y ----
    {
        const int mrow = t + HALO_R;
#pragma unroll
        for (int j = 0; j < CH_G; ++j) {
            float4 xv = buf[swz(mrow, j)];
            float4 ov;
#pragma unroll
            for (int q = 0; q < 4; ++q) {
                float xt = (&xv.x)[q];
                float yv = fmaf(b0, xt, s1);
                s1 = fmaf(b1, xt, s2);
                s1 = fmaf(na1, yv, s1);
                s2 = xt * b2;
                s2 = fmaf(na2, yv, s2);
                (&ov.x)[q] = yv;
            }
            buf[swz(mrow, j)] = ov;
        }
    }
    __syncthreads();

    // ---- store: LDS -> global, NON-TEMPORAL (evict-first: y must not
    //      allocate in the Infinity Cache and evict x). Native vector type
    //      required by the builtin. ----
#pragma unroll
    for (int i = 0; i < CH_G; ++i) {
        const int g = (i << 6) | t;
        float4 v = buf[swz(HALO_R + (g >> 3), g & 7)];
        floatv4 nv = { v.x, v.y, v.z, v.w };
        __builtin_nontemporal_store(nv, (floatv4*)&y4[base + g]);
    }
}

extern "C" void kernel_launch(void* const* d_in, const int* in_sizes, int n_in,
                              void* d_out, int out_size, void* d_ws, size_t ws_size,
                              hipStream_t stream)
{
    const float4* x4 = (const float4*)d_in[0];
    const float*  fr = (const float*)d_in[1];
    const float*  qr = (const float*)d_in[2];
    const float*  gn = (const float*)d_in[3];
    float4*       y4 = (float4*)d_out;

    int n_channels = in_sizes[0] / T_LEN;                 // 32
    int n_blocks   = n_channels * BLOCKS_PER_CHAN;        // 16384

    hipLaunchKernelGGL(peak_kernel, dim3(n_blocks), dim3(THREADS), 0, stream,
                       x4, fr, qr, gn, y4);
}